// Round 10
// baseline (46.147 us; speedup 1.0000x reference)
//
#include <hip/hip_runtime.h>
#include <math.h>

// Problem constants (fixed by reference setup_inputs)
#define BSZ   16
#define NA    3
#define NH    80
#define NW    80
#define NC    80
#define HW    (NH * NW)                 // 6400
#define CELLS (BSZ * NA * NH * NW)      // 307200
#define EPSL  1e-07f
#define BLK   256

// Class path: 64 cells per 256-thread block.
#define CLS_CB   64
#define NBLK_CLS (CELLS / CLS_CB)       // 4800
#define NBLK_BOX (CELLS / BLK)          // 1200
#define NBLK_TOT (NBLK_CLS + NBLK_BOX)  // 6000
#define PADS     65                     // LDS row stride (words) for tl2[ch][cell]

// ws layout: [0 .. NBLK_BOX*4)            box partials (xy, wh, iou, conf)
//            [WS_CLS .. WS_CLS+NBLK_CLS)  class partials
#define WS_CLS (NBLK_BOX * 4)           // 4800

#define L2E 1.4426950408889634f
#define LN2 0.6931471805599453f

__device__ __forceinline__ float fexp2(float x) { return __builtin_amdgcn_exp2f(x); }
__device__ __forceinline__ float flog2(float x) { return __builtin_amdgcn_logf(x); }
__device__ __forceinline__ float frcp(float x)  { return __builtin_amdgcn_rcpf(x); }

// max(z,0) - z*t + log1p(exp(-|z|)) via HW exp2/log2
__device__ __forceinline__ float bce_fast(float z, float t) {
    const float e  = fexp2(-fabsf(z) * L2E);
    const float sp = LN2 * flog2(1.0f + e);
    return fmaxf(z, 0.0f) - z * t + sp;
}

__device__ __forceinline__ float sigmoid_fast(float z) {
    return frcp(1.0f + fexp2(-z * L2E));
}

__global__ __launch_bounds__(BLK, 7) void yolo_loss_main(
    const float* __restrict__ input,
    const float* __restrict__ mask,
    const float* __restrict__ obj_mask,
    const float* __restrict__ tx,
    const float* __restrict__ ty,
    const float* __restrict__ tw,
    const float* __restrict__ th,
    const float* __restrict__ tgt_scale,
    const float* __restrict__ tcls,
    float* __restrict__ ws)
{
    __shared__ float red[4][4];
    const int tid  = threadIdx.x;
    const int lane = tid & 63;
    const int wid  = tid >> 6;
    const int bid  = blockIdx.x;

    if (bid < NBLK_CLS) {
        // ---- class-BCE: 64 cells/block; both tcls AND z read as float4 ----
        __shared__ float tl2[NC * PADS];            // [channel][cell], 20.8 KB
        const int B0    = bid * CLS_CB;             // first cell (64 | HW)
        const int plane = B0 / HW;
        const int hw0   = B0 % HW;                  // multiple of 64

        // tcls staging loads (5 float4, wave-contiguous)
        const float* tslab = tcls + (size_t)B0 * NC;
        float4 stg[5];
        #pragma unroll
        for (int k = 0; k < 5; ++k)
            stg[k] = *(const float4*)(tslab + 4 * (size_t)(tid + BLK * k));

        // z loads as float4: chunk c = tid+256k -> ch = c>>4, cells hch*4..+3
        // Per wave-instr: 4 channels x 256B contiguous, 100% line use.
        const float* zbase = input + (size_t)plane * (5 + NC) * HW
                           + (size_t)5 * HW + hw0;
        const int hch = tid & 15;                   // cell-quad, same for all k
        float z4[5][4];
        #pragma unroll
        for (int k = 0; k < 5; ++k) {
            const int ch = (tid + BLK * k) >> 4;    // 0..79
            *(float4*)z4[k] = *(const float4*)(zbase + (size_t)ch * HW + hch * 4);
        }
        float m4[4];
        *(float4*)m4 = *(const float4*)(mask + B0 + hch * 4);

        // LDS transposed stores (consume stg) — unchanged from R6
        #pragma unroll
        for (int k = 0; k < 5; ++k) {
            const int c  = tid + BLK * k;           // 16B-chunk id, 0..1279
            const int qc = c / 20;                  // cell in block
            const int g  = c % 20;                  // chunk within cell
            tl2[(4 * g + 0) * PADS + qc] = stg[k].x;
            tl2[(4 * g + 1) * PADS + qc] = stg[k].y;
            tl2[(4 * g + 2) * PADS + qc] = stg[k].z;
            tl2[(4 * g + 3) * PADS + qc] = stg[k].w;
        }
        __syncthreads();

        // Compute: thread owns cells hch*4..+3 for 5 channels (tid>>4 + 16k).
        // LDS reads: bank = (ch + 4*hch + j) mod 32 -> 2-way max (free).
        float acc[4] = {0.f, 0.f, 0.f, 0.f};
        #pragma unroll
        for (int k = 0; k < 5; ++k) {
            const int ch = (tid + BLK * k) >> 4;
            #pragma unroll
            for (int j = 0; j < 4; ++j)
                acc[j] += bce_fast(z4[k][j], tl2[ch * PADS + hch * 4 + j]);
        }
        float v = m4[0] * acc[0] + m4[1] * acc[1] + m4[2] * acc[2] + m4[3] * acc[3];

        #pragma unroll
        for (int off = 32; off > 0; off >>= 1)
            v += __shfl_down(v, off, 64);
        if (lane == 0) red[wid][0] = v;
        __syncthreads();
        if (tid == 0)
            ws[WS_CLS + bid] = red[0][0] + red[1][0] + red[2][0] + red[3][0];

    } else {
        // ------- box/conf/CIOU path: one cell per thread (coalesced) -------
        const int bbid  = bid - NBLK_CLS;
        const int cell  = bbid * BLK + tid;
        const int hw    = cell % HW;
        const int plane = cell / HW;

        const float* pbase = input + (size_t)plane * (5 + NC) * HW + hw;

        const float zx = pbase[0 * HW];
        const float zy = pbase[1 * HW];
        const float pw = pbase[2 * HW];
        const float ph = pbase[3 * HW];
        const float zc = pbase[4 * HW];

        const float m  = mask[cell];
        const float om = obj_mask[cell];
        const float gx = tx[cell];
        const float gy = ty[cell];
        const float gw = tw[cell];
        const float gh = th[cell];
        const float ts = tgt_scale[cell];

        const float x = sigmoid_fast(zx);
        const float y = sigmoid_fast(zy);

        float s_xy  = ts * (fabsf(x - gx) + fabsf(y - gy));
        float s_wh  = ts * (fabsf(pw - gw) + fabsf(ph - gh));
        float s_conf = om * bce_fast(zc, m);
        float s_iou;
        {
            const float p_x1 = x - pw * 0.5f, p_x2 = x + pw * 0.5f;
            const float p_y1 = y - ph * 0.5f, p_y2 = y + ph * 0.5f;
            const float g_x1 = gx - gw * 0.5f, g_x2 = gx + gw * 0.5f;
            const float g_y1 = gy - gh * 0.5f, g_y2 = gy + gh * 0.5f;

            const float iw = fmaxf(fminf(p_x2, g_x2) - fmaxf(p_x1, g_x1), 0.0f);
            const float ih = fmaxf(fminf(p_y2, g_y2) - fmaxf(p_y1, g_y1), 0.0f);
            const float inter = iw * ih;
            const float uni   = pw * ph + gw * gh - inter + EPSL;
            const float iou   = inter * frcp(uni);

            const float cw = fmaxf(p_x2, g_x2) - fminf(p_x1, g_x1);
            const float ch = fmaxf(p_y2, g_y2) - fminf(p_y1, g_y1);
            const float c2 = cw * cw + ch * ch + EPSL;
            const float rho2 = (x - gx) * (x - gx) + (y - gy) * (y - gy);

            const float da = atanf(gw * frcp(gh + EPSL))
                           - atanf(pw * frcp(ph + EPSL));
            const float v  = (4.0f / (float)(M_PI * M_PI)) * da * da;
            const float alpha = v * frcp(v - iou + 1.0f + EPSL);

            const float lbox = 1.0f - (iou - (rho2 * frcp(c2) + v * alpha));
            s_iou = m * ts * lbox;
        }

        float vals[4] = { s_xy, s_wh, s_iou, s_conf };
        #pragma unroll
        for (int j = 0; j < 4; ++j) {
            float v = vals[j];
            #pragma unroll
            for (int off = 32; off > 0; off >>= 1)
                v += __shfl_down(v, off, 64);
            vals[j] = v;
        }
        if (lane == 0) {
            #pragma unroll
            for (int j = 0; j < 4; ++j) red[wid][j] = vals[j];
        }
        __syncthreads();
        if (tid == 0) {
            #pragma unroll
            for (int j = 0; j < 4; ++j)
                ws[(size_t)bbid * 4 + j] =
                    red[0][j] + red[1][j] + red[2][j] + red[3][j];
        }
    }
}

// Deterministic final reduction: one block, fixed order -> identical every replay.
__global__ __launch_bounds__(BLK) void yolo_loss_final(
    const float* __restrict__ ws, float* __restrict__ out)
{
    __shared__ float red[4];
    const int lane = threadIdx.x & 63;
    const int wid  = threadIdx.x >> 6;
    const float scale4[4] = { 1.0f / (BSZ * BSZ), 1.0f / (BSZ * BSZ),
                              1.0f / BSZ, 1.0f / BSZ };

    for (int j = 0; j < 4; ++j) {
        float v = 0.f;
        for (int i = threadIdx.x; i < NBLK_BOX; i += BLK)
            v += ws[(size_t)i * 4 + j];
        #pragma unroll
        for (int off = 32; off > 0; off >>= 1)
            v += __shfl_down(v, off, 64);
        if (lane == 0) red[wid] = v;
        __syncthreads();
        if (threadIdx.x == 0)
            out[j] = (red[0] + red[1] + red[2] + red[3]) * scale4[j];
        __syncthreads();
    }
    {
        float v = 0.f;
        for (int i = threadIdx.x; i < NBLK_CLS; i += BLK)
            v += ws[WS_CLS + i];
        #pragma unroll
        for (int off = 32; off > 0; off >>= 1)
            v += __shfl_down(v, off, 64);
        if (lane == 0) red[wid] = v;
        __syncthreads();
        if (threadIdx.x == 0)
            out[4] = (red[0] + red[1] + red[2] + red[3]) * (1.0f / BSZ);
    }
}

extern "C" void kernel_launch(void* const* d_in, const int* in_sizes, int n_in,
                              void* d_out, int out_size, void* d_ws, size_t ws_size,
                              hipStream_t stream) {
    const float* input     = (const float*)d_in[0];
    const float* mask      = (const float*)d_in[1];
    const float* obj_mask  = (const float*)d_in[2];
    const float* tx        = (const float*)d_in[3];
    const float* ty        = (const float*)d_in[4];
    const float* tw        = (const float*)d_in[5];
    const float* th        = (const float*)d_in[6];
    const float* tgt_scale = (const float*)d_in[7];
    const float* tcls      = (const float*)d_in[8];
    float* out = (float*)d_out;
    float* ws  = (float*)d_ws;   // needs (4800 + 4800)*4 = 38400 bytes

    yolo_loss_main<<<NBLK_TOT, BLK, 0, stream>>>(
        input, mask, obj_mask, tx, ty, tw, th, tgt_scale, tcls, ws);
    yolo_loss_final<<<1, BLK, 0, stream>>>(ws, out);
}

// Round 11
// 44.781 us; speedup vs baseline: 1.0305x; 1.0305x over previous
//
#include <hip/hip_runtime.h>
#include <math.h>

// Problem constants (fixed by reference setup_inputs)
#define BSZ   16
#define NA    3
#define NH    80
#define NW    80
#define NC    80
#define HW    (NH * NW)                 // 6400
#define CELLS (BSZ * NA * NH * NW)      // 307200
#define EPSL  1e-07f
#define BLK   256

// Class path: 64 cells per 256-thread block, 4 lanes per cell (20 ch each).
#define CLS_CB   64
#define NBLK_CLS (CELLS / CLS_CB)       // 4800
#define NBLK_BOX (CELLS / BLK)          // 1200
#define NBLK_TOT (NBLK_CLS + NBLK_BOX)  // 6000
#define PADH     66                     // LDS row stride (halfwords) for tl2[ch][cell]

// ws layout: [0 .. NBLK_BOX*4)            box partials (xy, wh, iou, conf)
//            [WS_CLS .. WS_CLS+NBLK_CLS)  class partials
#define WS_CLS (NBLK_BOX * 4)           // 4800

#define L2E 1.4426950408889634f
#define LN2 0.6931471805599453f

__device__ __forceinline__ float fexp2(float x) { return __builtin_amdgcn_exp2f(x); }
__device__ __forceinline__ float flog2(float x) { return __builtin_amdgcn_logf(x); }
__device__ __forceinline__ float frcp(float x)  { return __builtin_amdgcn_rcpf(x); }

// max(z,0) - z*t + log1p(exp(-|z|)) via HW exp2/log2
__device__ __forceinline__ float bce_fast(float z, float t) {
    const float e  = fexp2(-fabsf(z) * L2E);
    const float sp = LN2 * flog2(1.0f + e);
    return fmaxf(z, 0.0f) - z * t + sp;
}

__device__ __forceinline__ float sigmoid_fast(float z) {
    return frcp(1.0f + fexp2(-z * L2E));
}

// f32 -> bf16 (round-half-up; exact for 0.0/1.0) and back (shift only)
__device__ __forceinline__ unsigned short f2bf(float x) {
    return (unsigned short)((__float_as_uint(x) + 0x8000u) >> 16);
}
__device__ __forceinline__ float bf2f(unsigned short u) {
    return __uint_as_float(((unsigned int)u) << 16);
}

__global__ __launch_bounds__(BLK, 8) void yolo_loss_main(
    const float* __restrict__ input,
    const float* __restrict__ mask,
    const float* __restrict__ obj_mask,
    const float* __restrict__ tx,
    const float* __restrict__ ty,
    const float* __restrict__ tw,
    const float* __restrict__ th,
    const float* __restrict__ tgt_scale,
    const float* __restrict__ tcls,
    float* __restrict__ ws)
{
    __shared__ float red[4][4];
    const int tid  = threadIdx.x;
    const int lane = tid & 63;
    const int wid  = tid >> 6;
    const int bid  = blockIdx.x;

    if (bid < NBLK_CLS) {
        // ---- class-BCE: 64 cells/block, tcls staged via LDS as bf16 ----
        __shared__ unsigned short tl2[NC * PADH];   // [channel][cell], 10.56 KB
        const int B0    = bid * CLS_CB;             // first cell (64 | HW)
        const int plane = B0 / HW;
        const int hw0   = B0 % HW;

        // Phase 1: flat contiguous copy of 64*320B tcls slab -> LDS (bf16, transposed)
        const float* tslab = tcls + (size_t)B0 * NC;
        float4 stg[5];
        #pragma unroll
        for (int k = 0; k < 5; ++k)
            stg[k] = *(const float4*)(tslab + 4 * (size_t)(tid + BLK * k));

        #pragma unroll
        for (int k = 0; k < 5; ++k) {
            const int c  = tid + BLK * k;           // 16B-chunk id, 0..1279
            const int qc = c / 20;                  // cell in block
            const int g  = c % 20;                  // chunk within cell
            tl2[(4 * g + 0) * PADH + qc] = f2bf(stg[k].x);
            tl2[(4 * g + 1) * PADH + qc] = f2bf(stg[k].y);
            tl2[(4 * g + 2) * PADH + qc] = f2bf(stg[k].z);
            tl2[(4 * g + 3) * PADH + qc] = f2bf(stg[k].w);
        }
        __syncthreads();

        // Phase 2: thread (q, p) does channels [20p, 20p+20) of cell B0+q
        const int q = tid >> 2;
        const int p = tid & 3;
        const float* zb = input + (size_t)plane * (5 + NC) * HW
                        + (size_t)(5 + 20 * p) * HW + hw0 + q;
        float z[20];
        #pragma unroll
        for (int i = 0; i < 20; ++i)
            z[i] = zb[(size_t)i * HW];              // 20 loads in flight
        float acc = 0.f;
        #pragma unroll
        for (int i = 0; i < 20; ++i)
            acc += bce_fast(z[i], bf2f(tl2[(20 * p + i) * PADH + q]));
        float v = mask[B0 + q] * acc;

        #pragma unroll
        for (int off = 32; off > 0; off >>= 1)
            v += __shfl_down(v, off, 64);
        if (lane == 0) red[wid][0] = v;
        __syncthreads();
        if (tid == 0)
            ws[WS_CLS + bid] = red[0][0] + red[1][0] + red[2][0] + red[3][0];

    } else {
        // ------- box/conf/CIOU path: one cell per thread (coalesced) -------
        const int bbid  = bid - NBLK_CLS;
        const int cell  = bbid * BLK + tid;
        const int hw    = cell % HW;
        const int plane = cell / HW;

        const float* pbase = input + (size_t)plane * (5 + NC) * HW + hw;

        const float zx = pbase[0 * HW];
        const float zy = pbase[1 * HW];
        const float pw = pbase[2 * HW];
        const float ph = pbase[3 * HW];
        const float zc = pbase[4 * HW];

        const float m  = mask[cell];
        const float om = obj_mask[cell];
        const float gx = tx[cell];
        const float gy = ty[cell];
        const float gw = tw[cell];
        const float gh = th[cell];
        const float ts = tgt_scale[cell];

        const float x = sigmoid_fast(zx);
        const float y = sigmoid_fast(zy);

        float s_xy  = ts * (fabsf(x - gx) + fabsf(y - gy));
        float s_wh  = ts * (fabsf(pw - gw) + fabsf(ph - gh));
        float s_conf = om * bce_fast(zc, m);
        float s_iou;
        {
            const float p_x1 = x - pw * 0.5f, p_x2 = x + pw * 0.5f;
            const float p_y1 = y - ph * 0.5f, p_y2 = y + ph * 0.5f;
            const float g_x1 = gx - gw * 0.5f, g_x2 = gx + gw * 0.5f;
            const float g_y1 = gy - gh * 0.5f, g_y2 = gy + gh * 0.5f;

            const float iw = fmaxf(fminf(p_x2, g_x2) - fmaxf(p_x1, g_x1), 0.0f);
            const float ih = fmaxf(fminf(p_y2, g_y2) - fmaxf(p_y1, g_y1), 0.0f);
            const float inter = iw * ih;
            const float uni   = pw * ph + gw * gh - inter + EPSL;
            const float iou   = inter * frcp(uni);

            const float cw = fmaxf(p_x2, g_x2) - fminf(p_x1, g_x1);
            const float ch = fmaxf(p_y2, g_y2) - fminf(p_y1, g_y1);
            const float c2 = cw * cw + ch * ch + EPSL;
            const float rho2 = (x - gx) * (x - gx) + (y - gy) * (y - gy);

            const float da = atanf(gw * frcp(gh + EPSL))
                           - atanf(pw * frcp(ph + EPSL));
            const float v  = (4.0f / (float)(M_PI * M_PI)) * da * da;
            const float alpha = v * frcp(v - iou + 1.0f + EPSL);

            const float lbox = 1.0f - (iou - (rho2 * frcp(c2) + v * alpha));
            s_iou = m * ts * lbox;
        }

        float vals[4] = { s_xy, s_wh, s_iou, s_conf };
        #pragma unroll
        for (int j = 0; j < 4; ++j) {
            float v = vals[j];
            #pragma unroll
            for (int off = 32; off > 0; off >>= 1)
                v += __shfl_down(v, off, 64);
            vals[j] = v;
        }
        if (lane == 0) {
            #pragma unroll
            for (int j = 0; j < 4; ++j) red[wid][j] = vals[j];
        }
        __syncthreads();
        if (tid == 0) {
            #pragma unroll
            for (int j = 0; j < 4; ++j)
                ws[(size_t)bbid * 4 + j] =
                    red[0][j] + red[1][j] + red[2][j] + red[3][j];
        }
    }
}

// Deterministic final reduction: one block, fixed order -> identical every replay.
__global__ __launch_bounds__(BLK) void yolo_loss_final(
    const float* __restrict__ ws, float* __restrict__ out)
{
    __shared__ float red[4];
    const int lane = threadIdx.x & 63;
    const int wid  = threadIdx.x >> 6;
    const float scale4[4] = { 1.0f / (BSZ * BSZ), 1.0f / (BSZ * BSZ),
                              1.0f / BSZ, 1.0f / BSZ };

    for (int j = 0; j < 4; ++j) {
        float v = 0.f;
        for (int i = threadIdx.x; i < NBLK_BOX; i += BLK)
            v += ws[(size_t)i * 4 + j];
        #pragma unroll
        for (int off = 32; off > 0; off >>= 1)
            v += __shfl_down(v, off, 64);
        if (lane == 0) red[wid] = v;
        __syncthreads();
        if (threadIdx.x == 0)
            out[j] = (red[0] + red[1] + red[2] + red[3]) * scale4[j];
        __syncthreads();
    }
    {
        float v = 0.f;
        for (int i = threadIdx.x; i < NBLK_CLS; i += BLK)
            v += ws[WS_CLS + i];
        #pragma unroll
        for (int off = 32; off > 0; off >>= 1)
            v += __shfl_down(v, off, 64);
        if (lane == 0) red[wid] = v;
        __syncthreads();
        if (threadIdx.x == 0)
            out[4] = (red[0] + red[1] + red[2] + red[3]) * (1.0f / BSZ);
    }
}

extern "C" void kernel_launch(void* const* d_in, const int* in_sizes, int n_in,
                              void* d_out, int out_size, void* d_ws, size_t ws_size,
                              hipStream_t stream) {
    const float* input     = (const float*)d_in[0];
    const float* mask      = (const float*)d_in[1];
    const float* obj_mask  = (const float*)d_in[2];
    const float* tx        = (const float*)d_in[3];
    const float* ty        = (const float*)d_in[4];
    const float* tw        = (const float*)d_in[5];
    const float* th        = (const float*)d_in[6];
    const float* tgt_scale = (const float*)d_in[7];
    const float* tcls      = (const float*)d_in[8];
    float* out = (float*)d_out;
    float* ws  = (float*)d_ws;   // needs (4800 + 4800)*4 = 38400 bytes

    yolo_loss_main<<<NBLK_TOT, BLK, 0, stream>>>(
        input, mask, obj_mask, tx, ty, tw, th, tgt_scale, tcls, ws);
    yolo_loss_final<<<1, BLK, 0, stream>>>(ws, out);
}

// Round 12
// 38.413 us; speedup vs baseline: 1.2013x; 1.1658x over previous
//
#include <hip/hip_runtime.h>
#include <math.h>

// Problem constants (fixed by reference setup_inputs)
#define BSZ   16
#define NA    3
#define NH    80
#define NW    80
#define NC    80
#define HW    (NH * NW)                 // 6400
#define CELLS (BSZ * NA * NH * NW)      // 307200
#define EPSL  1e-07f
#define BLK   256

// Class path: 64 cells per 256-thread block, 4 lanes per cell (20 ch each).
#define CLS_CB   64
#define NBLK_CLS (CELLS / CLS_CB)       // 4800
#define NBLK_BOX (CELLS / BLK)          // 1200
#define NBLK_TOT (NBLK_CLS + NBLK_BOX)  // 6000
#define PADH     66                     // LDS row stride (halfwords) for tl2[ch][cell]

// ws layout (floats, SoA): [j*NBLK_BOX + b] j=0..3 box partials (xy, wh, iou, conf)
//                          [WS_CLS + b]    class partials
#define WS_CLS (NBLK_BOX * 4)           // 4800

#define L2E 1.4426950408889634f
#define LN2 0.6931471805599453f

__device__ __forceinline__ float fexp2(float x) { return __builtin_amdgcn_exp2f(x); }
__device__ __forceinline__ float flog2(float x) { return __builtin_amdgcn_logf(x); }
__device__ __forceinline__ float frcp(float x)  { return __builtin_amdgcn_rcpf(x); }

// max(z,0) - z*t + log1p(exp(-|z|)) via HW exp2/log2
__device__ __forceinline__ float bce_fast(float z, float t) {
    const float e  = fexp2(-fabsf(z) * L2E);
    const float sp = LN2 * flog2(1.0f + e);
    return fmaxf(z, 0.0f) - z * t + sp;
}

__device__ __forceinline__ float sigmoid_fast(float z) {
    return frcp(1.0f + fexp2(-z * L2E));
}

// f32 -> bf16 (round-half-up; exact for 0.0/1.0) and back (shift only)
__device__ __forceinline__ unsigned short f2bf(float x) {
    return (unsigned short)((__float_as_uint(x) + 0x8000u) >> 16);
}
__device__ __forceinline__ float bf2f(unsigned short u) {
    return __uint_as_float(((unsigned int)u) << 16);
}

__global__ __launch_bounds__(BLK, 8) void yolo_loss_main(
    const float* __restrict__ input,
    const float* __restrict__ mask,
    const float* __restrict__ obj_mask,
    const float* __restrict__ tx,
    const float* __restrict__ ty,
    const float* __restrict__ tw,
    const float* __restrict__ th,
    const float* __restrict__ tgt_scale,
    const float* __restrict__ tcls,
    float* __restrict__ ws)
{
    __shared__ float red[4][4];
    const int tid  = threadIdx.x;
    const int lane = tid & 63;
    const int wid  = tid >> 6;
    const int bid  = blockIdx.x;

    if (bid < NBLK_CLS) {
        // ---- class-BCE: 64 cells/block, tcls staged via LDS as bf16 ----
        __shared__ unsigned short tl2[NC * PADH];   // [channel][cell], 10.56 KB
        const int B0    = bid * CLS_CB;             // first cell (64 | HW)
        const int plane = B0 / HW;
        const int hw0   = B0 % HW;

        // Phase 1: flat contiguous copy of 64*320B tcls slab -> LDS (bf16, transposed)
        const float* tslab = tcls + (size_t)B0 * NC;
        float4 stg[5];
        #pragma unroll
        for (int k = 0; k < 5; ++k)
            stg[k] = *(const float4*)(tslab + 4 * (size_t)(tid + BLK * k));

        #pragma unroll
        for (int k = 0; k < 5; ++k) {
            const int c  = tid + BLK * k;           // 16B-chunk id, 0..1279
            const int qc = c / 20;                  // cell in block
            const int g  = c % 20;                  // chunk within cell
            tl2[(4 * g + 0) * PADH + qc] = f2bf(stg[k].x);
            tl2[(4 * g + 1) * PADH + qc] = f2bf(stg[k].y);
            tl2[(4 * g + 2) * PADH + qc] = f2bf(stg[k].z);
            tl2[(4 * g + 3) * PADH + qc] = f2bf(stg[k].w);
        }
        __syncthreads();

        // Phase 2: thread (q, p) does channels [20p, 20p+20) of cell B0+q
        const int q = tid >> 2;
        const int p = tid & 3;
        const float* zb = input + (size_t)plane * (5 + NC) * HW
                        + (size_t)(5 + 20 * p) * HW + hw0 + q;
        float z[20];
        #pragma unroll
        for (int i = 0; i < 20; ++i)
            z[i] = zb[(size_t)i * HW];              // 20 loads in flight
        float acc = 0.f;
        #pragma unroll
        for (int i = 0; i < 20; ++i)
            acc += bce_fast(z[i], bf2f(tl2[(20 * p + i) * PADH + q]));
        float v = mask[B0 + q] * acc;

        #pragma unroll
        for (int off = 32; off > 0; off >>= 1)
            v += __shfl_down(v, off, 64);
        if (lane == 0) red[wid][0] = v;
        __syncthreads();
        if (tid == 0)
            ws[WS_CLS + bid] = red[0][0] + red[1][0] + red[2][0] + red[3][0];

    } else {
        // ------- box/conf/CIOU path: one cell per thread (coalesced) -------
        const int bbid  = bid - NBLK_CLS;
        const int cell  = bbid * BLK + tid;
        const int hw    = cell % HW;
        const int plane = cell / HW;

        const float* pbase = input + (size_t)plane * (5 + NC) * HW + hw;

        const float zx = pbase[0 * HW];
        const float zy = pbase[1 * HW];
        const float pw = pbase[2 * HW];
        const float ph = pbase[3 * HW];
        const float zc = pbase[4 * HW];

        const float m  = mask[cell];
        const float om = obj_mask[cell];
        const float gx = tx[cell];
        const float gy = ty[cell];
        const float gw = tw[cell];
        const float gh = th[cell];
        const float ts = tgt_scale[cell];

        const float x = sigmoid_fast(zx);
        const float y = sigmoid_fast(zy);

        float s_xy  = ts * (fabsf(x - gx) + fabsf(y - gy));
        float s_wh  = ts * (fabsf(pw - gw) + fabsf(ph - gh));
        float s_conf = om * bce_fast(zc, m);
        float s_iou;
        {
            const float p_x1 = x - pw * 0.5f, p_x2 = x + pw * 0.5f;
            const float p_y1 = y - ph * 0.5f, p_y2 = y + ph * 0.5f;
            const float g_x1 = gx - gw * 0.5f, g_x2 = gx + gw * 0.5f;
            const float g_y1 = gy - gh * 0.5f, g_y2 = gy + gh * 0.5f;

            const float iw = fmaxf(fminf(p_x2, g_x2) - fmaxf(p_x1, g_x1), 0.0f);
            const float ih = fmaxf(fminf(p_y2, g_y2) - fmaxf(p_y1, g_y1), 0.0f);
            const float inter = iw * ih;
            const float uni   = pw * ph + gw * gh - inter + EPSL;
            const float iou   = inter * frcp(uni);

            const float cw = fmaxf(p_x2, g_x2) - fminf(p_x1, g_x1);
            const float ch = fmaxf(p_y2, g_y2) - fminf(p_y1, g_y1);
            const float c2 = cw * cw + ch * ch + EPSL;
            const float rho2 = (x - gx) * (x - gx) + (y - gy) * (y - gy);

            const float da = atanf(gw * frcp(gh + EPSL))
                           - atanf(pw * frcp(ph + EPSL));
            const float v  = (4.0f / (float)(M_PI * M_PI)) * da * da;
            const float alpha = v * frcp(v - iou + 1.0f + EPSL);

            const float lbox = 1.0f - (iou - (rho2 * frcp(c2) + v * alpha));
            s_iou = m * ts * lbox;
        }

        float vals[4] = { s_xy, s_wh, s_iou, s_conf };
        #pragma unroll
        for (int j = 0; j < 4; ++j) {
            float v = vals[j];
            #pragma unroll
            for (int off = 32; off > 0; off >>= 1)
                v += __shfl_down(v, off, 64);
            vals[j] = v;
        }
        if (lane == 0) {
            #pragma unroll
            for (int j = 0; j < 4; ++j) red[wid][j] = vals[j];
        }
        __syncthreads();
        if (tid == 0) {
            #pragma unroll
            for (int j = 0; j < 4; ++j)
                ws[(size_t)j * NBLK_BOX + bbid] =
                    red[0][j] + red[1][j] + red[2][j] + red[3][j];
        }
    }
}

// Final reduction: 5 blocks, one per output. Fixed per-thread stride order,
// fixed shuffle tree -> bit-identical every replay. All loads float4.
__global__ __launch_bounds__(BLK) void yolo_loss_final(
    const float* __restrict__ ws, float* __restrict__ out)
{
    __shared__ float red[4];
    const int tid  = threadIdx.x;
    const int lane = tid & 63;
    const int wid  = tid >> 6;
    const int j    = blockIdx.x;    // 0..4

    const float scale[5] = { 1.0f / (BSZ * BSZ), 1.0f / (BSZ * BSZ),
                             1.0f / BSZ, 1.0f / BSZ, 1.0f / BSZ };

    const float* seg = (j < 4) ? (ws + (size_t)j * NBLK_BOX) : (ws + WS_CLS);
    const int    n4  = ((j < 4) ? NBLK_BOX : NBLK_CLS) / 4;   // 300 or 1200

    const float4* s4 = (const float4*)seg;
    float v = 0.f;
    for (int i = tid; i < n4; i += BLK) {
        const float4 t = s4[i];
        v += t.x + t.y + t.z + t.w;
    }
    #pragma unroll
    for (int off = 32; off > 0; off >>= 1)
        v += __shfl_down(v, off, 64);
    if (lane == 0) red[wid] = v;
    __syncthreads();
    if (tid == 0)
        out[j] = (red[0] + red[1] + red[2] + red[3]) * scale[j];
}

extern "C" void kernel_launch(void* const* d_in, const int* in_sizes, int n_in,
                              void* d_out, int out_size, void* d_ws, size_t ws_size,
                              hipStream_t stream) {
    const float* input     = (const float*)d_in[0];
    const float* mask      = (const float*)d_in[1];
    const float* obj_mask  = (const float*)d_in[2];
    const float* tx        = (const float*)d_in[3];
    const float* ty        = (const float*)d_in[4];
    const float* tw        = (const float*)d_in[5];
    const float* th        = (const float*)d_in[6];
    const float* tgt_scale = (const float*)d_in[7];
    const float* tcls      = (const float*)d_in[8];
    float* out = (float*)d_out;
    float* ws  = (float*)d_ws;   // needs (4800 + 4800)*4 = 38400 bytes

    yolo_loss_main<<<NBLK_TOT, BLK, 0, stream>>>(
        input, mask, obj_mask, tx, ty, tw, th, tgt_scale, tcls, ws);
    yolo_loss_final<<<5, BLK, 0, stream>>>(ws, out);
}